// Round 8
// baseline (2126.375 us; speedup 1.0000x reference)
//
#include <hip/hip_runtime.h>

// Clipped shallow PLRNN — packed-FMA + minimal-LDS + pinned-weight version.
// z_{t+1} = A*z_t + (relu(z@W2+h2) - relu(z@W2)) @ W1 + h1 ; x_t = z_t@OB + Ob
// n_states=64, n_hidden=256, bs=256, nt=4096. One row per CU (256 WGs x 256 thr).
//
// Round-7 finding: VGPR_Count=92 < 144 weight floats -> compiler rematerialized
// weight loads inside the 4096-step loop (L1 thrash: 36KB/CU > 32KB L1).
// Fix: amdgpu_waves_per_eu(1,1) (512-VGPR budget) + asm "+v" pins on all
// weight registers to make rematerialization illegal.

#define NS 64
#define NH 256
#define BS 256

typedef float v2f __attribute__((ext_vector_type(2)));

#define PIN(x) asm volatile("" : "+v"(x))

__device__ __forceinline__ float dppx1(float x) {  // quad_perm [1,0,3,2] == xor 1
    return __int_as_float(__builtin_amdgcn_mov_dpp(__float_as_int(x), 0xB1, 0xF, 0xF, true));
}
__device__ __forceinline__ float dppx2(float x) {  // quad_perm [2,3,0,1] == xor 2
    return __int_as_float(__builtin_amdgcn_mov_dpp(__float_as_int(x), 0x4E, 0xF, 0xF, true));
}
__device__ __forceinline__ float dppror8(float x) { // row_ror:8 == xor 8 within 16-lane row
    return __int_as_float(__builtin_amdgcn_mov_dpp(__float_as_int(x), 0x128, 0xF, 0xF, true));
}

__global__ __launch_bounds__(256) __attribute__((amdgpu_waves_per_eu(1, 1)))
void plrnn_kernel(const float* __restrict__ z0,
                  const float* __restrict__ A,
                  const float* __restrict__ W1,   // [NH][NS]
                  const float* __restrict__ W2,   // [NS][NH]
                  const float* __restrict__ h1,
                  const float* __restrict__ h2,
                  const float* __restrict__ OB,   // [NS][NS]
                  const float* __restrict__ Ob,
                  const int* __restrict__ ntp,
                  float* __restrict__ X)          // [BS][nt+1][NS]
{
    const int b    = blockIdx.x;
    const int tid  = threadIdx.x;
    const int g    = tid >> 2;    // phase1/obs output index
    const int s    = tid & 3;     // phase1/obs slice
    const int w    = tid >> 6;    // wave
    const int lane = tid & 63;
    const int nt   = *ntp;
    const bool s1  = (s & 1) != 0;
    const bool s2b = (s & 2) != 0;

    // phase2 lane decomposition
    const int b0 = lane & 1, b1 = (lane >> 1) & 1, b2 = (lane >> 2) & 1;
    const int b4 = (lane >> 4) & 1;
    const bool bb0 = b0 != 0, bb1 = b1 != 0;
    const int S2 = b0 | (b1 << 1) | (((lane >> 3) & 1) << 2) | (((lane >> 5) & 1) << 3);
    const int obase  = 16 * w + 4 * (b2 | (b4 << 1));  // 4 outputs obase..obase+3
    const int o_lane = obase + 2 * b1 + b0;            // this lane's final output

    __shared__ __align__(16) float zsh[NS];
    __shared__ __align__(16) float phish[4 * 68];      // producing wave w' at 68*w'

    // ---- weights in registers, packed in pairs along the reduction dim ----
    v2f w2p[4][8];   // w2p[j][k2] = {W2[16s+2k2][4g+j], W2[16s+2k2+1][4g+j]}
    #pragma unroll
    for (int k2 = 0; k2 < 8; ++k2) {
        const int r0 = 16 * s + 2 * k2;
        const float4 a0 = *reinterpret_cast<const float4*>(&W2[(r0 + 0) * NH + 4 * g]);
        const float4 a1 = *reinterpret_cast<const float4*>(&W2[(r0 + 1) * NH + 4 * g]);
        w2p[0][k2] = (v2f){a0.x, a1.x};
        w2p[1][k2] = (v2f){a0.y, a1.y};
        w2p[2][k2] = (v2f){a0.z, a1.z};
        w2p[3][k2] = (v2f){a0.w, a1.w};
    }
    v2f w1p[4][8];   // w1p[j][t2] = {W1[16*S2+2t2][obase+j], W1[16*S2+2t2+1][obase+j]}
    #pragma unroll
    for (int t2 = 0; t2 < 8; ++t2) {
        const int r0 = 16 * S2 + 2 * t2;
        const float4 a0 = *reinterpret_cast<const float4*>(&W1[(r0 + 0) * NS + obase]);
        const float4 a1 = *reinterpret_cast<const float4*>(&W1[(r0 + 1) * NS + obase]);
        w1p[0][t2] = (v2f){a0.x, a1.x};
        w1p[1][t2] = (v2f){a0.y, a1.y};
        w1p[2][t2] = (v2f){a0.z, a1.z};
        w1p[3][t2] = (v2f){a0.w, a1.w};
    }
    v2f obp[8];      // obp[k2] = {OB[16s+2k2][g], OB[16s+2k2+1][g]}
    #pragma unroll
    for (int k2 = 0; k2 < 8; ++k2)
        obp[k2] = (v2f){OB[(16 * s + 2 * k2) * NS + g], OB[(16 * s + 2 * k2 + 1) * NS + g]};

    // ---- pin all weight registers: forbids remat-from-global in the loop ----
    #pragma unroll
    for (int j = 0; j < 4; ++j) {
        #pragma unroll
        for (int k = 0; k < 8; ++k) { PIN(w2p[j][k]); PIN(w1p[j][k]); }
    }
    #pragma unroll
    for (int k = 0; k < 8; ++k) PIN(obp[k]);

    const float hA  = A[o_lane];
    const float hh1 = h1[o_lane];
    const float hh2 = h2[tid];
    const float hOb = Ob[g];
    float zcur = z0[b * NS + o_lane];   // z[o_lane], 4 copies across (b3,b5)

    if (tid < NS) zsh[tid] = z0[b * NS + tid];
    __syncthreads();

    float* __restrict__ Xb = X + (size_t)b * (size_t)(nt + 1) * NS;
    const float4* zs4  = reinterpret_cast<const float4*>(zsh) + 4 * s;
    const float4* ph4b = reinterpret_cast<const float4*>(phish + 68 * (S2 >> 2) + 16 * (S2 & 3));

    for (int t = 0; t < nt; ++t) {
        // ---- z slice s -> registers (4x b128, broadcast, <=2-way alias) ----
        const float4 za = zs4[0], zb = zs4[1], zc = zs4[2], zd = zs4[3];
        const v2f zz2[8] = {{za.x, za.y}, {za.z, za.w}, {zb.x, zb.y}, {zb.z, zb.w},
                            {zc.x, zc.y}, {zc.z, zc.w}, {zd.x, zd.y}, {zd.z, zd.w}};

        // ---- phase1 packed partials: hidden outputs 4g..4g+3 over slice s ----
        v2f q0 = {0.f, 0.f}, q1 = {0.f, 0.f}, q2 = {0.f, 0.f}, q3 = {0.f, 0.f};
        #pragma unroll
        for (int k2 = 0; k2 < 8; ++k2) {
            q0 = __builtin_elementwise_fma(zz2[k2], w2p[0][k2], q0);
            q1 = __builtin_elementwise_fma(zz2[k2], w2p[1][k2], q1);
            q2 = __builtin_elementwise_fma(zz2[k2], w2p[2][k2], q2);
            q3 = __builtin_elementwise_fma(zz2[k2], w2p[3][k2], q3);
        }
        const float p0 = q0.x + q0.y, p1 = q1.x + q1.y, p2 = q2.x + q2.y, p3 = q3.x + q3.y;

        // ---- obs packed partial (reuses zz2) ----
        v2f xop = {0.f, 0.f};
        #pragma unroll
        for (int k2 = 0; k2 < 8; ++k2) xop = __builtin_elementwise_fma(zz2[k2], obp[k2], xop);

        // ---- phase1 quad reduce-scatter -> W2z[tid] ----
        float sA = s1 ? p0 : p1;  float rA = dppx1(sA);  float k0 = (s1 ? p1 : p0) + rA;
        float sB = s1 ? p2 : p3;  float rB = dppx1(sB);  float k1 = (s1 ? p3 : p2) + rB;
        float sC = s2b ? k0 : k1; float rC = dppx2(sC);  float W2z = (s2b ? k1 : k0) + rC;

        const float ph = fmaxf(W2z + hh2, 0.f) - fmaxf(W2z, 0.f);
        phish[w * 68 + lane] = ph;

        // ---- obs full quad reduce + store ----
        float xr = xop.x + xop.y;
        xr += dppx1(xr);
        xr += dppx2(xr);
        if (s == 0) Xb[(size_t)t * NS + g] = xr + hOb;

        __syncthreads();   // phi visible; zsh reads of step t complete

        // ---- phase2: 16 phi values (4x b128), 4 packed output-partials ----
        const float4 f0 = ph4b[0], f1 = ph4b[1], f2 = ph4b[2], f3 = ph4b[3];
        const v2f ff[8] = {{f0.x, f0.y}, {f0.z, f0.w}, {f1.x, f1.y}, {f1.z, f1.w},
                           {f2.x, f2.y}, {f2.z, f2.w}, {f3.x, f3.y}, {f3.z, f3.w}};
        v2f u0 = {0.f, 0.f}, u1 = {0.f, 0.f}, u2 = {0.f, 0.f}, u3 = {0.f, 0.f};
        #pragma unroll
        for (int t2 = 0; t2 < 8; ++t2) {
            u0 = __builtin_elementwise_fma(ff[t2], w1p[0][t2], u0);
            u1 = __builtin_elementwise_fma(ff[t2], w1p[1][t2], u1);
            u2 = __builtin_elementwise_fma(ff[t2], w1p[2][t2], u2);
            u3 = __builtin_elementwise_fma(ff[t2], w1p[3][t2], u3);
        }
        const float v0 = u0.x + u0.y, v1 = u1.x + u1.y, v2 = u2.x + u2.y, v3 = u3.x + u3.y;

        // scatter over b0 (xor1), b1 (xor2); reduce over b3 (ror8), b5 (shfl 32)
        float tA = bb0 ? v0 : v1;  float wA = dppx1(tA);  float kA = (bb0 ? v1 : v0) + wA;
        float tB = bb0 ? v2 : v3;  float wB = dppx1(tB);  float kB = (bb0 ? v3 : v2) + wB;
        float tC = bb1 ? kA : kB;  float wC = dppx2(tC);  float P  = (bb1 ? kB : kA) + wC;
        P += dppror8(P);
        P += __shfl_xor(P, 32);

        zcur = fmaf(hA, zcur, P + hh1);              // identical on all 4 (b3,b5) copies
        if ((lane & 40) == 0) zsh[o_lane] = zcur;    // 16 lanes/wave, distinct banks

        __syncthreads();   // z_{t+1} visible; phish reads of step t complete
    }

    // ---- final observation x_nt ----
    {
        const float4 za = zs4[0], zb = zs4[1], zc = zs4[2], zd = zs4[3];
        const v2f zz2[8] = {{za.x, za.y}, {za.z, za.w}, {zb.x, zb.y}, {zb.z, zb.w},
                            {zc.x, zc.y}, {zc.z, zc.w}, {zd.x, zd.y}, {zd.z, zd.w}};
        v2f xop = {0.f, 0.f};
        #pragma unroll
        for (int k2 = 0; k2 < 8; ++k2) xop = __builtin_elementwise_fma(zz2[k2], obp[k2], xop);
        float xr = xop.x + xop.y;
        xr += dppx1(xr);
        xr += dppx2(xr);
        if (s == 0) Xb[(size_t)nt * NS + g] = xr + hOb;
    }
}

extern "C" void kernel_launch(void* const* d_in, const int* in_sizes, int n_in,
                              void* d_out, int out_size, void* d_ws, size_t ws_size,
                              hipStream_t stream) {
    const float* z0 = (const float*)d_in[0];
    const float* A  = (const float*)d_in[1];
    const float* W1 = (const float*)d_in[2];
    const float* W2 = (const float*)d_in[3];
    const float* h1 = (const float*)d_in[4];
    const float* h2 = (const float*)d_in[5];
    const float* OB = (const float*)d_in[6];
    const float* Ob = (const float*)d_in[7];
    const int*   ntp = (const int*)d_in[8];
    float* X = (float*)d_out;

    plrnn_kernel<<<BS, 256, 0, stream>>>(z0, A, W1, W2, h1, h2, OB, Ob, ntp, X);
}

// Round 9
// 2108.597 us; speedup vs baseline: 1.0084x; 1.0084x over previous
//
#include <hip/hip_runtime.h>

// Clipped shallow PLRNN — raw-barrier (no vmcnt drain) + permlane32 + overlapped-obs.
// z_{t+1} = A*z_t + (relu(z@W2+h2) - relu(z@W2)) @ W1 + h1 ; x_t = z_t@OB + Ob
// n_states=64, n_hidden=256, bs=256, nt=4096. One row per CU (256 WGs x 256 thr).
//
// Round-8 finding: weight residency doesn't matter (VGPR 92->132, dur flat).
// Critical path = __syncthreads() vmcnt(0) drain (X store ack every step) +
// ds_bpermute shfl32 + unhidden phi-read latency. This round removes all three:
//   1) raw `s_waitcnt lgkmcnt(0); s_barrier` (LDS handoffs only; X has no
//      in-block reader, so skipping the vmcnt drain is correct),
//   2) v_permlane32_swap (VALU) for the xor-32 reduce,
//   3) obs compute + X store moved between phi ds_read issue and use.

#define NS 64
#define NH 256
#define BS 256

typedef float v2f __attribute__((ext_vector_type(2)));
typedef unsigned int v2u __attribute__((ext_vector_type(2)));

#define PIN(x) asm volatile("" : "+v"(x))
// LDS-only barrier: waits local ops, skips vmcnt/expcnt drain that
// __syncthreads() would add for the (reader-less) global X stores.
#define BAR() asm volatile("s_waitcnt lgkmcnt(0)\ns_barrier" ::: "memory")

__device__ __forceinline__ float dppx1(float x) {  // quad_perm [1,0,3,2] == xor 1
    return __int_as_float(__builtin_amdgcn_mov_dpp(__float_as_int(x), 0xB1, 0xF, 0xF, true));
}
__device__ __forceinline__ float dppx2(float x) {  // quad_perm [2,3,0,1] == xor 2
    return __int_as_float(__builtin_amdgcn_mov_dpp(__float_as_int(x), 0x4E, 0xF, 0xF, true));
}
__device__ __forceinline__ float dppror8(float x) { // row_ror:8 == xor 8 within 16-lane row
    return __int_as_float(__builtin_amdgcn_mov_dpp(__float_as_int(x), 0x128, 0xF, 0xF, true));
}
__device__ __forceinline__ float xor32sum(float x) { // x + x_from(lane^32), VALU permlane
    v2u r = __builtin_amdgcn_permlane32_swap(__float_as_uint(x), __float_as_uint(x), false, false);
    return __uint_as_float(r.x) + __uint_as_float(r.y);
}

__global__ __launch_bounds__(256) __attribute__((amdgpu_waves_per_eu(1, 1)))
void plrnn_kernel(const float* __restrict__ z0,
                  const float* __restrict__ A,
                  const float* __restrict__ W1,   // [NH][NS]
                  const float* __restrict__ W2,   // [NS][NH]
                  const float* __restrict__ h1,
                  const float* __restrict__ h2,
                  const float* __restrict__ OB,   // [NS][NS]
                  const float* __restrict__ Ob,
                  const int* __restrict__ ntp,
                  float* __restrict__ X)          // [BS][nt+1][NS]
{
    const int b    = blockIdx.x;
    const int tid  = threadIdx.x;
    const int g    = tid >> 2;    // phase1/obs output index
    const int s    = tid & 3;     // phase1/obs slice
    const int w    = tid >> 6;    // wave
    const int lane = tid & 63;
    const int nt   = *ntp;
    const bool s1  = (s & 1) != 0;
    const bool s2b = (s & 2) != 0;

    // phase2 lane decomposition
    const int b0 = lane & 1, b1 = (lane >> 1) & 1, b2 = (lane >> 2) & 1;
    const int b4 = (lane >> 4) & 1;
    const bool bb0 = b0 != 0, bb1 = b1 != 0;
    const int S2 = b0 | (b1 << 1) | (((lane >> 3) & 1) << 2) | (((lane >> 5) & 1) << 3);
    const int obase  = 16 * w + 4 * (b2 | (b4 << 1));  // 4 outputs obase..obase+3
    const int o_lane = obase + 2 * b1 + b0;            // this lane's final output

    __shared__ __align__(16) float zsh[NS];
    __shared__ __align__(16) float phish[4 * 68];      // producing wave w' at 68*w'

    // ---- weights in registers, packed in pairs along the reduction dim ----
    v2f w2p[4][8];   // w2p[j][k2] = {W2[16s+2k2][4g+j], W2[16s+2k2+1][4g+j]}
    #pragma unroll
    for (int k2 = 0; k2 < 8; ++k2) {
        const int r0 = 16 * s + 2 * k2;
        const float4 a0 = *reinterpret_cast<const float4*>(&W2[(r0 + 0) * NH + 4 * g]);
        const float4 a1 = *reinterpret_cast<const float4*>(&W2[(r0 + 1) * NH + 4 * g]);
        w2p[0][k2] = (v2f){a0.x, a1.x};
        w2p[1][k2] = (v2f){a0.y, a1.y};
        w2p[2][k2] = (v2f){a0.z, a1.z};
        w2p[3][k2] = (v2f){a0.w, a1.w};
    }
    v2f w1p[4][8];   // w1p[j][t2] = {W1[16*S2+2t2][obase+j], W1[16*S2+2t2+1][obase+j]}
    #pragma unroll
    for (int t2 = 0; t2 < 8; ++t2) {
        const int r0 = 16 * S2 + 2 * t2;
        const float4 a0 = *reinterpret_cast<const float4*>(&W1[(r0 + 0) * NS + obase]);
        const float4 a1 = *reinterpret_cast<const float4*>(&W1[(r0 + 1) * NS + obase]);
        w1p[0][t2] = (v2f){a0.x, a1.x};
        w1p[1][t2] = (v2f){a0.y, a1.y};
        w1p[2][t2] = (v2f){a0.z, a1.z};
        w1p[3][t2] = (v2f){a0.w, a1.w};
    }
    v2f obp[8];      // obp[k2] = {OB[16s+2k2][g], OB[16s+2k2+1][g]}
    #pragma unroll
    for (int k2 = 0; k2 < 8; ++k2)
        obp[k2] = (v2f){OB[(16 * s + 2 * k2) * NS + g], OB[(16 * s + 2 * k2 + 1) * NS + g]};

    // ---- pin all weight registers: forbids remat-from-global in the loop ----
    #pragma unroll
    for (int j = 0; j < 4; ++j) {
        #pragma unroll
        for (int k = 0; k < 8; ++k) { PIN(w2p[j][k]); PIN(w1p[j][k]); }
    }
    #pragma unroll
    for (int k = 0; k < 8; ++k) PIN(obp[k]);

    const float hA  = A[o_lane];
    const float hh1 = h1[o_lane];
    const float hh2 = h2[tid];
    const float hOb = Ob[g];
    float zcur = z0[b * NS + o_lane];   // z[o_lane], 4 copies across (b3,b5)

    if (tid < NS) zsh[tid] = z0[b * NS + tid];
    __syncthreads();

    float* __restrict__ Xb = X + (size_t)b * (size_t)(nt + 1) * NS;
    const float4* zs4  = reinterpret_cast<const float4*>(zsh) + 4 * s;
    const float4* ph4b = reinterpret_cast<const float4*>(phish + 68 * (S2 >> 2) + 16 * (S2 & 3));

    for (int t = 0; t < nt; ++t) {
        // ---- z slice s -> registers (4x b128, broadcast, <=2-way alias) ----
        const float4 za = zs4[0], zb = zs4[1], zc = zs4[2], zd = zs4[3];
        const v2f zz2[8] = {{za.x, za.y}, {za.z, za.w}, {zb.x, zb.y}, {zb.z, zb.w},
                            {zc.x, zc.y}, {zc.z, zc.w}, {zd.x, zd.y}, {zd.z, zd.w}};

        // ---- phase1 packed partials: hidden outputs 4g..4g+3 over slice s ----
        v2f q0 = {0.f, 0.f}, q1 = {0.f, 0.f}, q2 = {0.f, 0.f}, q3 = {0.f, 0.f};
        #pragma unroll
        for (int k2 = 0; k2 < 8; ++k2) {
            q0 = __builtin_elementwise_fma(zz2[k2], w2p[0][k2], q0);
            q1 = __builtin_elementwise_fma(zz2[k2], w2p[1][k2], q1);
            q2 = __builtin_elementwise_fma(zz2[k2], w2p[2][k2], q2);
            q3 = __builtin_elementwise_fma(zz2[k2], w2p[3][k2], q3);
        }
        const float p0 = q0.x + q0.y, p1 = q1.x + q1.y, p2 = q2.x + q2.y, p3 = q3.x + q3.y;

        // ---- phase1 quad reduce-scatter -> W2z[tid] ----
        float sA = s1 ? p0 : p1;  float rA = dppx1(sA);  float k0 = (s1 ? p1 : p0) + rA;
        float sB = s1 ? p2 : p3;  float rB = dppx1(sB);  float k1 = (s1 ? p3 : p2) + rB;
        float sC = s2b ? k0 : k1; float rC = dppx2(sC);  float W2z = (s2b ? k1 : k0) + rC;

        const float ph = fmaxf(W2z + hh2, 0.f) - fmaxf(W2z, 0.f);
        phish[w * 68 + lane] = ph;

        BAR();             // phi visible; zsh reads of step t complete (LDS-only wait)

        // ---- phase2 phi reads issued first; obs below hides their latency ----
        const float4 f0 = ph4b[0], f1 = ph4b[1], f2 = ph4b[2], f3 = ph4b[3];

        // ---- obs (uses zz2 regs): packed dot + quad reduce + global store ----
        v2f xop = {0.f, 0.f};
        #pragma unroll
        for (int k2 = 0; k2 < 8; ++k2) xop = __builtin_elementwise_fma(zz2[k2], obp[k2], xop);
        float xr = xop.x + xop.y;
        xr += dppx1(xr);
        xr += dppx2(xr);
        if (s == 0) Xb[(size_t)t * NS + g] = xr + hOb;   // fire-and-forget (no drain)

        // ---- phase2: 4 packed output-partials over 16 phi ----
        const v2f ff[8] = {{f0.x, f0.y}, {f0.z, f0.w}, {f1.x, f1.y}, {f1.z, f1.w},
                           {f2.x, f2.y}, {f2.z, f2.w}, {f3.x, f3.y}, {f3.z, f3.w}};
        v2f u0 = {0.f, 0.f}, u1 = {0.f, 0.f}, u2 = {0.f, 0.f}, u3 = {0.f, 0.f};
        #pragma unroll
        for (int t2 = 0; t2 < 8; ++t2) {
            u0 = __builtin_elementwise_fma(ff[t2], w1p[0][t2], u0);
            u1 = __builtin_elementwise_fma(ff[t2], w1p[1][t2], u1);
            u2 = __builtin_elementwise_fma(ff[t2], w1p[2][t2], u2);
            u3 = __builtin_elementwise_fma(ff[t2], w1p[3][t2], u3);
        }
        const float v0 = u0.x + u0.y, v1 = u1.x + u1.y, v2 = u2.x + u2.y, v3 = u3.x + u3.y;

        // scatter over b0 (xor1), b1 (xor2); reduce over b3 (ror8), b5 (permlane32)
        float tA = bb0 ? v0 : v1;  float wA = dppx1(tA);  float kA = (bb0 ? v1 : v0) + wA;
        float tB = bb0 ? v2 : v3;  float wB = dppx1(tB);  float kB = (bb0 ? v3 : v2) + wB;
        float tC = bb1 ? kA : kB;  float wC = dppx2(tC);  float P  = (bb1 ? kB : kA) + wC;
        P += dppror8(P);
        P = xor32sum(P);

        zcur = fmaf(hA, zcur, P + hh1);              // identical on all 4 (b3,b5) copies
        if ((lane & 40) == 0) zsh[o_lane] = zcur;    // 16 lanes/wave, distinct banks

        BAR();             // z_{t+1} visible; phish reads of step t complete
    }

    // ---- final observation x_nt ----
    {
        const float4 za = zs4[0], zb = zs4[1], zc = zs4[2], zd = zs4[3];
        const v2f zz2[8] = {{za.x, za.y}, {za.z, za.w}, {zb.x, zb.y}, {zb.z, zb.w},
                            {zc.x, zc.y}, {zc.z, zc.w}, {zd.x, zd.y}, {zd.z, zd.w}};
        v2f xop = {0.f, 0.f};
        #pragma unroll
        for (int k2 = 0; k2 < 8; ++k2) xop = __builtin_elementwise_fma(zz2[k2], obp[k2], xop);
        float xr = xop.x + xop.y;
        xr += dppx1(xr);
        xr += dppx2(xr);
        if (s == 0) Xb[(size_t)nt * NS + g] = xr + hOb;
    }
}

extern "C" void kernel_launch(void* const* d_in, const int* in_sizes, int n_in,
                              void* d_out, int out_size, void* d_ws, size_t ws_size,
                              hipStream_t stream) {
    const float* z0 = (const float*)d_in[0];
    const float* A  = (const float*)d_in[1];
    const float* W1 = (const float*)d_in[2];
    const float* W2 = (const float*)d_in[3];
    const float* h1 = (const float*)d_in[4];
    const float* h2 = (const float*)d_in[5];
    const float* OB = (const float*)d_in[6];
    const float* Ob = (const float*)d_in[7];
    const int*   ntp = (const int*)d_in[8];
    float* X = (float*)d_out;

    plrnn_kernel<<<BS, 256, 0, stream>>>(z0, A, W1, W2, h1, h2, OB, Ob, ntp, X);
}